// Round 8
// baseline (84172.418 us; speedup 1.0000x reference)
//
#include <hip/hip_runtime.h>
#include <hip/hip_bf16.h>

// LSTM autoencoder, 4 layers, XCD-colocated dataflow.
// Role assignment is LOCK-FREE claim-based (no global rendezvous): WGs on
// XCD l<4 claim layer-(l+1) slots natively; losers/others scan+claim with a
// mixed-flag mark. Slice 0 of each pool publishes the single FAST/SAFE
// decision (no member disagreement). FAST pools keep the latency-critical
// recurrence ring in their XCD's L2 (sc0: L1-bypass, L2-coherent); every
// 64th poll falls back to an agent-scope load so a stale-serving sc0 can
// delay but never deadlock the poll. Mixed pools use agent-scope (MALL)
// throughout. Cross-layer rings stay agent-scope, register-prefetched one
// step ahead. No vmcnt-draining __syncthreads in the main loop.

typedef __bf16 bf16x8 __attribute__((ext_vector_type(8)));
typedef float f32x4 __attribute__((ext_vector_type(4)));
typedef unsigned long long u64;

#define NWG_TOTAL 248
#define TSTEPS 1024
#define RDC 64   // cross-layer ring depth (gated by consumed flags)
#define RDL 16   // local recurrence ring depth (lockstep, ungated)
#define SENT (~0ull)
#define PACE_IDX 2040
// flags-region layout (u32 indices, all < 4096, zeroed by host memset):
//   gate flags: ((LAYER-1)*16+slice)*32  (max 1504)
//   claim[l]    at 1600 + 8*l
//   mixed[l]    at 1700 + 8*l
//   decision[l] at 1800 + 8*l
//   pace        at 2040

__device__ __forceinline__ f32x4 mfma16(bf16x8 a, bf16x8 b, f32x4 c) {
  return __builtin_amdgcn_mfma_f32_16x16x32_bf16(a, b, c, 0, 0, 0);
}
__device__ __forceinline__ float sigmoid_fast(float x) {
  return 1.0f / (1.0f + __expf(-x));
}
// agent-scope (cross-XCD, resolves at MALL)
__device__ __forceinline__ u64 load8_llc(const __bf16* p) {
  return __hip_atomic_load((const u64*)p, __ATOMIC_RELAXED,
                           __HIP_MEMORY_SCOPE_AGENT);
}
__device__ __forceinline__ void store8_llc(__bf16* p, u64 v) {
  __hip_atomic_store((u64*)p, v, __ATOMIC_RELAXED, __HIP_MEMORY_SCOPE_AGENT);
}
// small atomics for role assignment
__device__ __forceinline__ unsigned a_load(unsigned* p) {
  return __hip_atomic_load(p, __ATOMIC_RELAXED, __HIP_MEMORY_SCOPE_AGENT);
}
__device__ __forceinline__ unsigned a_load_acq(unsigned* p) {
  return __hip_atomic_load(p, __ATOMIC_ACQUIRE, __HIP_MEMORY_SCOPE_AGENT);
}
__device__ __forceinline__ unsigned a_faa_rel(unsigned* p, unsigned v) {
  return __hip_atomic_fetch_add(p, v, __ATOMIC_RELEASE,
                                __HIP_MEMORY_SCOPE_AGENT);
}
__device__ __forceinline__ void a_or_rel(unsigned* p, unsigned v) {
  __hip_atomic_fetch_or(p, v, __ATOMIC_RELEASE, __HIP_MEMORY_SCOPE_AGENT);
}
__device__ __forceinline__ void a_store_rel(unsigned* p, unsigned v) {
  __hip_atomic_store(p, v, __ATOMIC_RELEASE, __HIP_MEMORY_SCOPE_AGENT);
}
// XCD-local: sc0 = bypass L1, coherent at this XCD's shared L2
__device__ __forceinline__ void store8_sc0(__bf16* p, u64 v) {
  asm volatile("global_store_dwordx2 %0, %1, off sc0" :: "v"(p), "v"(v) : "memory");
}
__device__ __forceinline__ void sc0_load16(u64* d, const __bf16* base) {
  asm volatile(
      "global_load_dwordx2 %0, %16, off sc0\n\t"
      "global_load_dwordx2 %1, %16, off offset:8 sc0\n\t"
      "global_load_dwordx2 %2, %16, off offset:64 sc0\n\t"
      "global_load_dwordx2 %3, %16, off offset:72 sc0\n\t"
      "global_load_dwordx2 %4, %16, off offset:128 sc0\n\t"
      "global_load_dwordx2 %5, %16, off offset:136 sc0\n\t"
      "global_load_dwordx2 %6, %16, off offset:192 sc0\n\t"
      "global_load_dwordx2 %7, %16, off offset:200 sc0\n\t"
      "global_load_dwordx2 %8, %16, off offset:256 sc0\n\t"
      "global_load_dwordx2 %9, %16, off offset:264 sc0\n\t"
      "global_load_dwordx2 %10, %16, off offset:320 sc0\n\t"
      "global_load_dwordx2 %11, %16, off offset:328 sc0\n\t"
      "global_load_dwordx2 %12, %16, off offset:384 sc0\n\t"
      "global_load_dwordx2 %13, %16, off offset:392 sc0\n\t"
      "global_load_dwordx2 %14, %16, off offset:448 sc0\n\t"
      "global_load_dwordx2 %15, %16, off offset:456 sc0\n\t"
      "s_waitcnt vmcnt(0)"
      : "=&v"(d[0]), "=&v"(d[1]), "=&v"(d[2]), "=&v"(d[3]),
        "=&v"(d[4]), "=&v"(d[5]), "=&v"(d[6]), "=&v"(d[7]),
        "=&v"(d[8]), "=&v"(d[9]), "=&v"(d[10]), "=&v"(d[11]),
        "=&v"(d[12]), "=&v"(d[13]), "=&v"(d[14]), "=&v"(d[15])
      : "v"(base) : "memory");
}
__device__ __forceinline__ void sc0_load8(u64* d, const __bf16* base) {
  asm volatile(
      "global_load_dwordx2 %0, %8, off sc0\n\t"
      "global_load_dwordx2 %1, %8, off offset:8 sc0\n\t"
      "global_load_dwordx2 %2, %8, off offset:64 sc0\n\t"
      "global_load_dwordx2 %3, %8, off offset:72 sc0\n\t"
      "global_load_dwordx2 %4, %8, off offset:128 sc0\n\t"
      "global_load_dwordx2 %5, %8, off offset:136 sc0\n\t"
      "global_load_dwordx2 %6, %8, off offset:192 sc0\n\t"
      "global_load_dwordx2 %7, %8, off offset:200 sc0\n\t"
      "s_waitcnt vmcnt(0)"
      : "=&v"(d[0]), "=&v"(d[1]), "=&v"(d[2]), "=&v"(d[3]),
        "=&v"(d[4]), "=&v"(d[5]), "=&v"(d[6]), "=&v"(d[7])
      : "v"(base) : "memory");
}
__device__ __forceinline__ bf16x8 frag_of(u64 lo, u64 hi) {
  union { bf16x8 v; u64 d[2]; } u; u.d[0] = lo; u.d[1] = hi; return u.v;
}
__device__ __forceinline__ void wg_barrier() {
  asm volatile("" ::: "memory");
  __builtin_amdgcn_s_barrier();
  asm volatile("" ::: "memory");
}
__device__ __forceinline__ void wg_barrier_lds() {  // my LDS writes done, then meet
  asm volatile("s_waitcnt lgkmcnt(0)" ::: "memory");
  __builtin_amdgcn_s_barrier();
  asm volatile("" ::: "memory");
}
__device__ __forceinline__ void wait_vm0() {
  asm volatile("s_waitcnt vmcnt(0)" ::: "memory");
}

// One layer, one 16-hcol slice. Wave w: batch rows [16w,16w+16).
template <int F, int H, int LAYER, int NDOWN, bool FAST>
__device__ void layer_run(const float* __restrict__ xg,
                          const __bf16* __restrict__ rin,   // prev layer cross ring
                          const float* __restrict__ W, const float* __restrict__ U,
                          const float* __restrict__ bias,
                          __bf16* __restrict__ rloc,        // local ring [RDL][64][H]
                          __bf16* __restrict__ rnext,       // cross ring [RDC][64][H]
                          float* __restrict__ out,
                          unsigned* flags, int slice, __bf16* smem) {
  constexpr int KW = F / 32;
  constexpr int KU = H / 32;
  constexpr int FOURH = 4 * H;
  const int tid = threadIdx.x;
  const int wave = tid >> 6;
  const int lane = tid & 63;
  const int l15 = lane & 15;
  const int q = lane >> 4;
  const int hcol = slice * 16 + l15;
  const int brow = wave * 16;
  const int srow = tid >> 2, scg = tid & 3;

  float bz[4];
#pragma unroll
  for (int nt = 0; nt < 4; ++nt) bz[nt] = bias[nt * H + hcol];

  // ---- one-time: stage W,U slice to LDS, extract B-frags to registers ----
  bf16x8 wf[4][KW];
  bf16x8 uf[4][KU];
  for (int idx = tid; idx < F * 64; idx += 256) {
    int k = idx >> 6, c = idx & 63;
    int col = (c >> 4) * H + slice * 16 + (c & 15);
    smem[c * F + k] = (__bf16)W[k * FOURH + col];
  }
  __syncthreads();
#pragma unroll
  for (int nt = 0; nt < 4; ++nt)
#pragma unroll
    for (int kk = 0; kk < KW; ++kk)
      wf[nt][kk] = *(const bf16x8*)&smem[(nt * 16 + l15) * F + kk * 32 + q * 8];
  __syncthreads();
  for (int idx = tid; idx < H * 64; idx += 256) {
    int k = idx >> 6, c = idx & 63;
    int col = (c >> 4) * H + slice * 16 + (c & 15);
    smem[c * H + k] = (__bf16)U[k * FOURH + col];
  }
  __syncthreads();
#pragma unroll
  for (int nt = 0; nt < 4; ++nt)
#pragma unroll
    for (int kk = 0; kk < KU; ++kk)
      uf[nt][kk] = *(const bf16x8*)&smem[(nt * 16 + l15) * H + kk * 32 + q * 8];
  __syncthreads();

  __bf16* hlds = smem;  // reused as 64x16 transpose tile
  float c_state[4] = {0.f, 0.f, 0.f, 0.f};

  // cross-layer input prefetch state (one slot ahead)
  u64 rx[(LAYER > 1) ? 2 * KW : 2];
  if constexpr (LAYER > 1) {
    const __bf16* xr0 = rin + (size_t)(brow + l15) * F + q * 8;  // slot 0
#pragma unroll
    for (int kk = 0; kk < KW; ++kk) {
      rx[2 * kk] = load8_llc(xr0 + kk * 32);
      rx[2 * kk + 1] = load8_llc(xr0 + kk * 32 + 4);
    }
  }

  for (int t = 0; t < TSTEPS; ++t) {
    // ---- cross-layer anti-dep gate, every 16 steps (off critical path) ----
    if (NDOWN > 0 && (t & 15) == 0 && t >= 48) {
      if (wave == 0) {
        const bool act = lane < NDOWN;
        unsigned* fp = &flags[((LAYER - 1) * 16 + (act ? lane : 0)) * 32];
        while (true) {
          unsigned v = __hip_atomic_load(fp, __ATOMIC_RELAXED,
                                         __HIP_MEMORY_SCOPE_AGENT);
          if (!__ballot(act && (int)v < t - 32)) break;
          __builtin_amdgcn_s_sleep(2);
        }
      }
      wg_barrier();
    }

    // ---- L1: x loads for this step (in flight across the rh poll) ----
    float4 xf[(LAYER == 1) ? 2 * KW : 1];
    if constexpr (LAYER == 1) {
      const float* xrow = xg + ((size_t)(brow + l15) * 1024 + t) * 256 + q * 8;
#pragma unroll
      for (int kk = 0; kk < KW; ++kk) {
        const float4* p4 = (const float4*)(xrow + kk * 32);
        xf[2 * kk] = p4[0];
        xf[2 * kk + 1] = p4[1];
      }
    }

    // ---- recurrence poll: XCD-local L2 (FAST, with periodic agent-scope
    //      fallback so stale-serving sc0 can never deadlock) or agent (SAFE) ----
    u64 rh[2 * KU];
    if (t > 0) {
      const __bf16* rr = rloc + (size_t)((t - 1) & (RDL - 1)) * 64 * H +
                         (brow + l15) * H + q * 8;
      unsigned spin = 0;
      while (true) {
        bool use_fast = FAST && ((spin & 63u) != 63u);
        if (use_fast) {
          if constexpr (FAST) {
            if constexpr (KU == 8) sc0_load16(rh, rr); else sc0_load8(rh, rr);
          }
        } else {
#pragma unroll
          for (int kk = 0; kk < KU; ++kk) {
            rh[2 * kk] = load8_llc(rr + kk * 32);
            rh[2 * kk + 1] = load8_llc(rr + kk * 32 + 4);
          }
        }
        bool bad = false;
#pragma unroll
        for (int j = 0; j < 2 * KU; ++j) bad |= (rh[j] == SENT);
        if (!__ballot(bad)) break;
        ++spin;
        __builtin_amdgcn_s_sleep(1);
      }
    }

    // ---- cross-layer input: consume prefetched slot t (reload if early) ----
    if constexpr (LAYER > 1) {
      const __bf16* xr = rin + (size_t)(t & (RDC - 1)) * 64 * F +
                         (brow + l15) * F + q * 8;
      while (true) {
        bool bad = false;
#pragma unroll
        for (int j = 0; j < 2 * KW; ++j) bad |= (rx[j] == SENT);
        if (!__ballot(bad)) break;
        __builtin_amdgcn_s_sleep(1);
#pragma unroll
        for (int kk = 0; kk < KW; ++kk) {
          rx[2 * kk] = load8_llc(xr + kk * 32);
          rx[2 * kk + 1] = load8_llc(xr + kk * 32 + 4);
        }
      }
    }

    // ---- NaN-init slot t+1 (fire-and-forget; drained before data store) ----
    {
      const size_t po = (size_t)srow * H + slice * 16 + scg * 4;
      if constexpr (FAST)
        store8_sc0(rloc + (size_t)((t + 1) & (RDL - 1)) * 64 * H + po, SENT);
      else
        store8_llc(rloc + (size_t)((t + 1) & (RDL - 1)) * 64 * H + po, SENT);
      if constexpr (NDOWN > 0)
        store8_llc(rnext + (size_t)((t + 1) & (RDC - 1)) * 64 * H + po, SENT);
    }

    // ---- MFMA chain ----
    f32x4 acc[4] = {};
#pragma unroll
    for (int kk = 0; kk < KW; ++kk) {
      bf16x8 a;
      if constexpr (LAYER == 1) {
        float4 a0 = xf[2 * kk], a1 = xf[2 * kk + 1];
        a[0] = (__bf16)a0.x; a[1] = (__bf16)a0.y;
        a[2] = (__bf16)a0.z; a[3] = (__bf16)a0.w;
        a[4] = (__bf16)a1.x; a[5] = (__bf16)a1.y;
        a[6] = (__bf16)a1.z; a[7] = (__bf16)a1.w;
      } else {
        a = frag_of(rx[2 * kk], rx[2 * kk + 1]);
      }
#pragma unroll
      for (int nt = 0; nt < 4; ++nt) acc[nt] = mfma16(a, wf[nt][kk], acc[nt]);
    }
    if (t > 0) {
#pragma unroll
      for (int kk = 0; kk < KU; ++kk) {
        bf16x8 a = frag_of(rh[2 * kk], rh[2 * kk + 1]);
#pragma unroll
        for (int nt = 0; nt < 4; ++nt) acc[nt] = mfma16(a, uf[nt][kk], acc[nt]);
      }
    }

    // ---- gates + state update (lane-local) ----
    float hv[4];
#pragma unroll
    for (int r = 0; r < 4; ++r) {
      float zi = acc[0][r] + bz[0];
      float zf = acc[1][r] + bz[1];
      float zg = acc[2][r] + bz[2];
      float zo = acc[3][r] + bz[3];
      float ig = sigmoid_fast(zi);
      float fg = sigmoid_fast(zf);
      float gg = fmaxf(zg, 0.0f);
      float og = sigmoid_fast(zo);
      float cn = fg * c_state[r] + ig * gg;
      c_state[r] = cn;
      hv[r] = og * fmaxf(cn, 0.0f);
      hlds[(brow + q * 4 + r) * 16 + l15] = (__bf16)hv[r];
    }
    wg_barrier_lds();  // transpose tile complete (lgkm only, no vmcnt drain)

    // ---- packed data store; visibility IS the signal ----
    {
      u64 v = *(const u64*)&hlds[srow * 16 + scg * 4];
      wait_vm0();  // per-granule: my NaN(t+1) completes before my data(t)
      const size_t po = (size_t)srow * H + slice * 16 + scg * 4;
      if constexpr (FAST)
        store8_sc0(rloc + (size_t)(t & (RDL - 1)) * 64 * H + po, v);
      else
        store8_llc(rloc + (size_t)(t & (RDL - 1)) * 64 * H + po, v);
      if constexpr (NDOWN > 0)
        store8_llc(rnext + (size_t)(t & (RDC - 1)) * 64 * H + po, v);
    }
    if constexpr (LAYER == 4) {
#pragma unroll
      for (int r = 0; r < 4; ++r) {
        int b = brow + q * 4 + r;
        out[((size_t)b * 1024 + t) * 256 + hcol] = hv[r];
      }
    }
    wg_barrier();  // hlds reads done before next step's writes

    // ---- prefetch next cross-layer slot (hides MALL latency) ----
    if constexpr (LAYER > 1) {
      if (t + 1 < TSTEPS) {
        const __bf16* xr1 = rin + (size_t)((t + 1) & (RDC - 1)) * 64 * F +
                            (brow + l15) * F + q * 8;
#pragma unroll
        for (int kk = 0; kk < KW; ++kk) {
          rx[2 * kk] = load8_llc(xr1 + kk * 32);
          rx[2 * kk + 1] = load8_llc(xr1 + kk * 32 + 4);
        }
      }
    }
    // ---- consumed post for upstream producer (every 16 steps) ----
    if (LAYER > 1 && (t & 15) == 15 && tid == 0)
      __hip_atomic_store(&flags[((LAYER - 2) * 16 + slice) * 32],
                         (unsigned)(t + 1), __ATOMIC_RELAXED,
                         __HIP_MEMORY_SCOPE_AGENT);
    // ---- pace for x-prefetcher WGs ----
    if (LAYER == 1 && slice == 0 && tid == 0 && (t & 3) == 0)
      __hip_atomic_store(&flags[PACE_IDX], (unsigned)t, __ATOMIC_RELAXED,
                         __HIP_MEMORY_SCOPE_AGENT);
  }
}

// Idle claimed WGs warm x[:, t+2..t+8, :] into L2 (paced by L1's progress).
__device__ void x_prefetch(const float* __restrict__ xg, unsigned* flags, int p) {
  const int row = p * 16 + (threadIdx.x >> 4);
  const int coff = (threadIdx.x & 15) * 16;
  int done = 0;
  while (done < TSTEPS) {
    unsigned pace = __hip_atomic_load(&flags[PACE_IDX], __ATOMIC_RELAXED,
                                      __HIP_MEMORY_SCOPE_AGENT);
    int target = (int)pace + 8;
    if (target > TSTEPS - 1) target = TSTEPS - 1;
    while (done <= target) {
      const float* a = xg + ((size_t)row * 1024 + done) * 256 + coff;
      float dummy;
      asm volatile("global_load_dword %0, %1, off\n\ts_waitcnt vmcnt(0)"
                   : "=v"(dummy) : "v"(a) : "memory");
      ++done;
    }
    if (done >= TSTEPS) break;
    __builtin_amdgcn_s_sleep(8);
  }
}

struct KParams {
  const float* x;
  const float* W1; const float* U1; const float* b1;
  const float* W2; const float* U2; const float* b2;
  const float* W3; const float* U3; const float* b3;
  const float* W4; const float* U4; const float* b4;
  float* out;
  unsigned* flags;
  __bf16* l1; __bf16* l2; __bf16* l3; __bf16* l4;  // local rings
  __bf16* c1; __bf16* c2; __bf16* c3;              // cross rings
};

__global__ __launch_bounds__(256, 1) void lstm_kernel(KParams p) {
  __shared__ __align__(16) __bf16 smem[64 * 256];  // 32 KB staging
  __shared__ int bc[3];
  const int tid = threadIdx.x;

  // ---- lock-free claim-based role assignment (no global rendezvous) ----
  // pool l (= layer l+1) prefers XCD l. claim[l] >= need[l] <=> pool full.
  // Foreign claimants mark mixed BEFORE claiming (release); winners wait
  // pool-full (acquire), then slice 0 alone publishes the FAST/SAFE
  // decision so all members agree.
  if (tid == 0) {
    const int need[4] = {20, 8, 16, 16};
    unsigned* claim = &p.flags[1600];   // + 8*l
    unsigned* mixedf = &p.flags[1700];  // + 8*l
    unsigned* decis = &p.flags[1800];   // + 8*l
    unsigned xcc;
    asm volatile("s_getreg_b32 %0, hwreg(HW_REG_XCC_ID)" : "=s"(xcc));
    const int myx = (int)(xcc & 7);
    int pool = -1, slice = 0;
    if (myx < 4) {  // native claim
      unsigned idx = a_faa_rel(&claim[8 * myx], 1);
      if (idx < (unsigned)need[myx]) { pool = myx; slice = (int)idx; }
    }
    if (pool < 0) {  // foreign/loser: let natives claim first, then scan
      for (int i = 0; i < 4; ++i) __builtin_amdgcn_s_sleep(64);
      for (int pass = 0; pass < 2 && pool < 0; ++pass) {
        for (int l = 0; l < 4 && pool < 0; ++l) {
          if (a_load(&claim[8 * l]) >= (unsigned)need[l]) continue;  // full
          a_or_rel(&mixedf[8 * l], 1u);  // mark before claim (spurious ok)
          unsigned idx = a_faa_rel(&claim[8 * l], 1);
          if (idx < (unsigned)need[l]) { pool = l; slice = (int)idx; }
        }
      }
    }
    int fastm = 0;
    if (pool >= 0) {
      while (a_load_acq(&claim[8 * pool]) < (unsigned)need[pool])
        __builtin_amdgcn_s_sleep(8);
      if (slice == 0) {  // single arbiter publishes the decision
        unsigned m = a_load(&mixedf[8 * pool]);
        a_store_rel(&decis[8 * pool], 0x100u | (m ? 1u : 0u));
      }
      unsigned d;
      while ((((d = a_load_acq(&decis[8 * pool]))) & 0x100u) == 0)
        __builtin_amdgcn_s_sleep(8);
      fastm = ((d & 1u) == 0) ? 1 : 0;
    }
    bc[0] = pool; bc[1] = slice; bc[2] = fastm;
  }
  __syncthreads();
  const int myl = bc[0], slice = bc[1];
  const bool fast = (bc[2] != 0);
  if (myl < 0) return;  // spare WG: free the CU

  if (myl == 0) {
    if (slice >= 16) { x_prefetch(p.x, p.flags, slice - 16); return; }
    if (fast) layer_run<256, 256, 1, 8, true >(p.x, nullptr, p.W1, p.U1, p.b1, p.l1, p.c1, nullptr, p.flags, slice, smem);
    else      layer_run<256, 256, 1, 8, false>(p.x, nullptr, p.W1, p.U1, p.b1, p.l1, p.c1, nullptr, p.flags, slice, smem);
  } else if (myl == 1) {
    if (fast) layer_run<256, 128, 2, 16, true >(nullptr, p.c1, p.W2, p.U2, p.b2, p.l2, p.c2, nullptr, p.flags, slice, smem);
    else      layer_run<256, 128, 2, 16, false>(nullptr, p.c1, p.W2, p.U2, p.b2, p.l2, p.c2, nullptr, p.flags, slice, smem);
  } else if (myl == 2) {
    if (fast) layer_run<128, 256, 3, 16, true >(nullptr, p.c2, p.W3, p.U3, p.b3, p.l3, p.c3, nullptr, p.flags, slice, smem);
    else      layer_run<128, 256, 3, 16, false>(nullptr, p.c2, p.W3, p.U3, p.b3, p.l3, p.c3, nullptr, p.flags, slice, smem);
  } else {
    if (fast) layer_run<256, 256, 4, 0, true >(nullptr, p.c3, p.W4, p.U4, p.b4, p.l4, nullptr, p.out, p.flags, slice, smem);
    else      layer_run<256, 256, 4, 0, false>(nullptr, p.c3, p.W4, p.U4, p.b4, p.l4, nullptr, p.out, p.flags, slice, smem);
  }
}

extern "C" void kernel_launch(void* const* d_in, const int* in_sizes, int n_in,
                              void* d_out, int out_size, void* d_ws, size_t ws_size,
                              hipStream_t stream) {
  unsigned char* ws = (unsigned char*)d_ws;
  KParams p;
  p.x  = (const float*)d_in[0];
  p.W1 = (const float*)d_in[1];  p.U1 = (const float*)d_in[2];  p.b1 = (const float*)d_in[3];
  p.W2 = (const float*)d_in[4];  p.U2 = (const float*)d_in[5];  p.b2 = (const float*)d_in[6];
  p.W3 = (const float*)d_in[7];  p.U3 = (const float*)d_in[8];  p.b3 = (const float*)d_in[9];
  p.W4 = (const float*)d_in[10]; p.U4 = (const float*)d_in[11]; p.b4 = (const float*)d_in[12];
  p.out = (float*)d_out;
  p.flags = (unsigned*)ws;               // [0, 16KB): gates + claim/mixed/decision + pace
  size_t off = 16384;
  const size_t lb256 = (size_t)RDL * 64 * 256 * 2;  // 512 KB
  const size_t lb128 = (size_t)RDL * 64 * 128 * 2;  // 256 KB
  const size_t cb256 = (size_t)RDC * 64 * 256 * 2;  // 2 MB
  const size_t cb128 = (size_t)RDC * 64 * 128 * 2;  // 1 MB
  p.l1 = (__bf16*)(ws + off); off += lb256;
  p.l2 = (__bf16*)(ws + off); off += lb128;
  p.l3 = (__bf16*)(ws + off); off += lb256;
  p.l4 = (__bf16*)(ws + off); off += lb256;
  p.c1 = (__bf16*)(ws + off); off += cb256;
  p.c2 = (__bf16*)(ws + off); off += cb128;
  p.c3 = (__bf16*)(ws + off); off += cb256;

  hipMemsetAsync(ws, 0, 16384, stream);                    // flags/claims
  hipMemsetAsync(ws + 16384, 0xFF, off - 16384, stream);   // NaN all ring slots

  lstm_kernel<<<dim3(NWG_TOTAL), dim3(256), 0, stream>>>(p);
}